// Round 18
// baseline (124.589 us; speedup 1.0000x reference)
//
#include <hip/hip_runtime.h>
#include <math.h>

typedef __bf16 bf16_t;
typedef __bf16 bf16x4 __attribute__((ext_vector_type(4)));
typedef __bf16 bf16x8 __attribute__((ext_vector_type(8)));
typedef float f32x4 __attribute__((ext_vector_type(4)));

#define DIMC 256
#define HID 768
#define NB 8
#define NN 4096
#define ROWS (NB*NN)   /* 32768 */
#define NCHUNK 32

#define AS1 __attribute__((address_space(1)))
#define AS3 __attribute__((address_space(3)))

__device__ __forceinline__ void gll16(const bf16_t* src, void* lds) {
  __builtin_amdgcn_global_load_lds((const AS1 void*)src, (AS3 void*)lds, 16, 0, 0);
}

__device__ __forceinline__ float gelu_exact(float v) {
  return 0.5f * v * (1.0f + erff(v * 0.70710678118654752f));
}

// ---- pack weight w[K][Nw] (f32) into MFMA-fragment order bf16 (device body) ----
__device__ __forceinline__ void pack_w_body(int idx, const float* __restrict__ w,
                                            bf16_t* __restrict__ out, int K, int Nw) {
  int lane = idx & 63;
  int kq = (idx >> 6) % (K >> 5);
  int nt = idx / ((K >> 5) << 6);
  int n = nt * 16 + (lane & 15);
  int k0 = kq * 32 + (lane >> 4) * 8;
  bf16x8 o;
#pragma unroll
  for (int j = 0; j < 8; ++j) o[j] = (bf16_t)w[(size_t)(k0 + j) * Nw + n];
  *(bf16x8*)(out + (size_t)idx * 8) = o;
}

// ---------------- merged prep: x->bf16 + 3x weight pack (one dispatch) ----------------
__global__ __launch_bounds__(256)
void prep_all_kernel(const float* __restrict__ x, bf16_t* __restrict__ xb,
                     const float* __restrict__ w_qkv, bf16_t* __restrict__ Bq,
                     const float* __restrict__ w_fc1, bf16_t* __restrict__ B1,
                     const float* __restrict__ w_fc2, bf16_t* __restrict__ B2) {
  const int bid = blockIdx.x, tid = threadIdx.x;
  if (bid < 4096) {
    int i = (bid * 256 + tid) * 8;
    f32x4 a = *(const f32x4*)(x + i);
    f32x4 b = *(const f32x4*)(x + i + 4);
    bf16x8 o;
    o[0] = (bf16_t)a[0]; o[1] = (bf16_t)a[1]; o[2] = (bf16_t)a[2]; o[3] = (bf16_t)a[3];
    o[4] = (bf16_t)b[0]; o[5] = (bf16_t)b[1]; o[6] = (bf16_t)b[2]; o[7] = (bf16_t)b[3];
    *(bf16x8*)(xb + i) = o;
  } else if (bid < 4192) {
    pack_w_body((bid - 4096) * 256 + tid, w_qkv, Bq, 256, 768);
  } else if (bid < 4288) {
    pack_w_body((bid - 4192) * 256 + tid, w_fc1, B1, 256, 768);
  } else {
    pack_w_body((bid - 4288) * 256 + tid, w_fc2, B2, 768, 256);
  }
}

// ============ packed-B GEMM: C[M,768] = A[M,256] @ W + bias ============
// 32-row x 192-col tiles, grid 4096 blocks: acc[2][3]=24 AGPR, ~96 regs
// -> ~5 blocks/CU (~20 waves/CU) for latency hiding (r10 mechanism, 2nd dose).
// XCD-chunked swizzle; 2-deep B prefetch; B prologue overlaps A drain.
template <int EPI>
__global__ __launch_bounds__(256, 2)
void gemm_packed_kernel(const bf16_t* __restrict__ A, const bf16_t* __restrict__ Bp,
                        const float* __restrict__ bias, bf16_t* __restrict__ outp) {
  __shared__ __align__(16) unsigned char smem[16384];
  const int tid = threadIdx.x;
  const int d = blockIdx.x + blockIdx.y * 4;          // 0..4095
  const int w_ = (d & 7) * 512 + (d >> 3);            // XCD-chunked swizzle
  const int panel = w_ & 3, rowb = w_ >> 2;           // 4 panels x 1024 rowblocks
  const int m0 = rowb * 32;
  const int n0 = panel * 192;
  const int lane = tid & 63, w = tid >> 6;
  const int lr = lane & 15, lk = lane >> 4;

  // stage A 32x256 (full 512B rows) — 4 vmcnt units
#pragma unroll
  for (int i = 0; i < 4; ++i) {
    int idx = i * 256 + tid;            // 0..1023
    int row = idx >> 5, pk = idx & 31;
    gll16(A + (size_t)(m0 + row) * 256 + ((pk ^ (row & 7)) * 8), smem + idx * 16);
  }

  // issue B prologue loads NOW (6 vmcnt units) — latency hides under A drain
  const bf16_t* bb = Bp + (size_t)((panel * 12 + w * 3) * 8) * 512 + lane * 8;
  bf16x8 bf[3][3];
#pragma unroll
  for (int nf = 0; nf < 3; ++nf) {
    bf[0][nf] = *(const bf16x8*)(bb + (nf * 8 + 0) * 512);
    bf[1][nf] = *(const bf16x8*)(bb + (nf * 8 + 1) * 512);
  }

  asm volatile("s_waitcnt vmcnt(6)" ::: "memory");   // A done; B in flight
  __builtin_amdgcn_s_barrier();

  f32x4 acc[2][3] = {};
  bf16x8 af[2][2];   // rotating 2-slot A, 2 mi
#pragma unroll
  for (int mi = 0; mi < 2; ++mi) {
    int row = mi * 16 + lr;
    af[0][mi] = *(const bf16x8*)(smem + row * 512 + ((lk ^ (row & 7)) * 16));
  }

#pragma unroll
  for (int kq = 0; kq < 8; ++kq) {
    if (kq < 6) {
#pragma unroll
      for (int nf = 0; nf < 3; ++nf)
        bf[(kq + 2) % 3][nf] = *(const bf16x8*)(bb + (nf * 8 + kq + 2) * 512);
    }
    if (kq < 7) {
#pragma unroll
      for (int mi = 0; mi < 2; ++mi) {
        int row = mi * 16 + lr;
        af[(kq + 1) & 1][mi] =
            *(const bf16x8*)(smem + row * 512 + ((((kq + 1) * 4 + lk) ^ (row & 7)) * 16));
      }
    }
    __builtin_amdgcn_s_setprio(1);
#pragma unroll
    for (int nf = 0; nf < 3; ++nf)
#pragma unroll
      for (int mi = 0; mi < 2; ++mi)
        acc[mi][nf] = __builtin_amdgcn_mfma_f32_16x16x32_bf16(bf[kq % 3][nf], af[kq & 1][mi],
                                                              acc[mi][nf], 0, 0, 0);
    __builtin_amdgcn_s_setprio(0);
  }

  // ---- epilogue: reuse A-LDS (32 rows x 384B = 12KB), single phase ----
  f32x4 bs[3];
#pragma unroll
  for (int nf = 0; nf < 3; ++nf)
    bs[nf] = *(const f32x4*)(bias + n0 + w * 48 + nf * 16 + lk * 4);

  __syncthreads();
#pragma unroll
  for (int mi = 0; mi < 2; ++mi) {
    int row_l = mi * 16 + lr;
#pragma unroll
    for (int nf = 0; nf < 3; ++nf) {
      int col = w * 48 + nf * 16 + lk * 4;   // block-local 0..191
      f32x4 v = acc[mi][nf] + bs[nf];
      bf16x4 o;
#pragma unroll
      for (int r = 0; r < 4; ++r) {
        float val = v[r];
        if (EPI == 1) val = gelu_exact(val);
        o[r] = (bf16_t)val;
      }
      int chunk = col >> 3;
      int half = (col >> 2) & 1;
      *(bf16x4*)(smem + row_l * 384 + ((chunk ^ (row_l & 7)) << 4) + (half << 3)) = o;
    }
  }
  __syncthreads();
#pragma unroll
  for (int i = 0; i < 3; ++i) {
    int id = i * 256 + tid;             // 0..767
    int row_l = id / 24, c = id % 24;
    bf16x8 v = *(const bf16x8*)(smem + row_l * 384 + ((c ^ (row_l & 7)) << 4));
    *(bf16x8*)(outp + (size_t)(m0 + row_l) * 768 + n0 + c * 8) = v;
  }
}

// ============ fc2: out[M,256] = mid[M,768] @ W + bias + resid (f32 out) ============
__global__ __launch_bounds__(256, 2)
void fc2_packed_kernel(const bf16_t* __restrict__ mid, const bf16_t* __restrict__ Bp,
                       const float* __restrict__ bias, const bf16_t* __restrict__ resid,
                       float* __restrict__ outp) {
  __shared__ __align__(16) unsigned char smem[2 * 16384 + 32768];
  unsigned char* epi = smem + 32768;
  const int tid = threadIdx.x;
  const int m0 = blockIdx.x * 64;
  const int lane = tid & 63, w = tid >> 6;
  const int lr = lane & 15, lk = lane >> 4;

  auto stageA = [&](int c, int buf) {
#pragma unroll
    for (int i = 0; i < 4; ++i) {
      int idx = i * 256 + tid;
      int row = idx >> 4, pk = idx & 15;
      gll16(mid + (size_t)(m0 + row) * 768 + c * 128 + ((pk ^ (row & 7)) * 8),
            smem + buf * 16384 + idx * 16);
    }
  };

  stageA(0, 0);
  stageA(1, 1);
  asm volatile("s_waitcnt vmcnt(4)" ::: "memory");
  __builtin_amdgcn_s_barrier();

  f32x4 acc[4][4] = {};
#pragma unroll
  for (int c = 0; c < 6; ++c) {
    bf16x8 bf[4][4];
#pragma unroll
    for (int nf = 0; nf < 4; ++nf)
#pragma unroll
      for (int kql = 0; kql < 4; ++kql)
        bf[nf][kql] = *(const bf16x8*)(Bp + (size_t)((w * 4 + nf) * 24 + c * 4 + kql) * 512 + lane * 8);
    asm volatile("s_waitcnt vmcnt(0)" ::: "memory");
    __builtin_amdgcn_s_barrier();
#pragma unroll
    for (int kql = 0; kql < 4; ++kql) {
#pragma unroll
      for (int mi = 0; mi < 4; ++mi) {
        int row = mi * 16 + lr;
        bf16x8 a8 = *(const bf16x8*)(smem + (c & 1) * 16384 + row * 256 +
                                     (((kql * 4 + lk) ^ (row & 7)) * 16));
#pragma unroll
        for (int nf = 0; nf < 4; ++nf)
          acc[mi][nf] = __builtin_amdgcn_mfma_f32_16x16x32_bf16(bf[nf][kql], a8, acc[mi][nf], 0, 0, 0);
      }
    }
    __builtin_amdgcn_s_barrier();
    if (c + 2 < 6) stageA(c + 2, c & 1);
  }

  f32x4 bs[4];
#pragma unroll
  for (int nf = 0; nf < 4; ++nf)
    bs[nf] = *(const f32x4*)(bias + w * 64 + nf * 16 + lk * 4);

#pragma unroll
  for (int ph = 0; ph < 2; ++ph) {
    if (ph == 1) __syncthreads();
#pragma unroll
    for (int mj = 0; mj < 2; ++mj) {
      int mi = ph * 2 + mj;
      int row_l = mj * 16 + lr;
#pragma unroll
      for (int nf = 0; nf < 4; ++nf) {
        int cc = w * 64 + nf * 16 + lk * 4;
        f32x4 v = acc[mi][nf] + bs[nf];
        int chunk = cc >> 2;
        *(f32x4*)(epi + row_l * 1024 + ((chunk ^ (row_l & 7)) << 4)) = v;
      }
    }
    __syncthreads();
#pragma unroll
    for (int i = 0; i < 8; ++i) {
      int id = i * 256 + tid;
      int rl = id >> 6, c = id & 63;
      f32x4 v = *(const f32x4*)(epi + rl * 1024 + ((c ^ (rl & 7)) << 4));
      int grow = m0 + ph * 32 + rl;
      bf16x4 rz = *(const bf16x4*)(resid + (size_t)grow * 256 + c * 4);
#pragma unroll
      for (int r = 0; r < 4; ++r) v[r] += (float)rz[r];
      *(f32x4*)(outp + (size_t)grow * 256 + c * 4) = v;
    }
  }
}

// ---------------- attention: partial K^T V over N-chunks (VALU) ----------------
__global__ __launch_bounds__(256)
void attn_kv_kernel(const bf16_t* __restrict__ qkv, float* __restrict__ part) {
  const int bh = blockIdx.x, chunk = blockIdx.y;
  const int b = bh >> 2, h = bh & 3;
  __shared__ __align__(16) float kl[32][68];
  __shared__ __align__(16) float vl[32][68];
  const int tid = threadIdx.x;
  const int dg = tid >> 4, eg = tid & 15;
  f32x4 acc[4] = {};
  const int n00 = chunk * (NN / NCHUNK);
  const int srow = tid >> 3, spk = tid & 7;
  for (int t = 0; t < (NN / NCHUNK) / 32; ++t) {
    int n0 = n00 + t * 32;
    {
      const bf16x8 k8 = *(const bf16x8*)(qkv + (size_t)(b * NN + n0 + srow) * HID + 256 + h * 64 + spk * 8);
      const bf16x8 v8 = *(const bf16x8*)(qkv + (size_t)(b * NN + n0 + srow) * HID + 512 + h * 64 + spk * 8);
#pragma unroll
      for (int j = 0; j < 8; ++j) kl[srow][spk * 8 + j] = (float)k8[j];
#pragma unroll
      for (int j = 0; j < 8; ++j) vl[srow][spk * 8 + j] = (float)v8[j];
    }
    __syncthreads();
#pragma unroll 8
    for (int n = 0; n < 32; ++n) {
      f32x4 k4 = *(const f32x4*)&kl[n][dg * 4];
      f32x4 v4 = *(const f32x4*)&vl[n][eg * 4];
#pragma unroll
      for (int i = 0; i < 4; ++i) acc[i] += k4[i] * v4;
    }
    __syncthreads();
  }
  float* dst = part + (size_t)(chunk * 32 + bh) * 4096;
#pragma unroll
  for (int i = 0; i < 4; ++i)
    *(f32x4*)&dst[(dg * 4 + i) * 64 + eg * 4] = acc[i];
}

// ---------------- reduce partials + scale + softmax -> bf16 attn ----------------
__global__ __launch_bounds__(256)
void attn_softmax_kernel(const float* __restrict__ part, bf16_t* __restrict__ attnb) {
  const int bh = blockIdx.x, dg = blockIdx.y;
  const int tid = threadIdx.x;
  const int rl = tid >> 5, l32 = tid & 31;
  const int d = dg * 8 + rl;
  const size_t rowoff = (size_t)d * 64 + l32 * 2;
  float s0 = 0.f, s1 = 0.f;
  for (int c = 0; c < NCHUNK; ++c) {
    const float* src = part + (size_t)(c * 32 + bh) * 4096 + rowoff;
    s0 += src[0]; s1 += src[1];
  }
  float l0 = s0 * 0.125f, l1 = s1 * 0.125f;
  float m = fmaxf(l0, l1);
#pragma unroll
  for (int msk = 1; msk <= 16; msk <<= 1) m = fmaxf(m, __shfl_xor(m, msk));
  float p0 = expf(l0 - m), p1 = expf(l1 - m);
  float sum = p0 + p1;
#pragma unroll
  for (int msk = 1; msk <= 16; msk <<= 1) sum += __shfl_xor(sum, msk);
  float inv = 1.0f / sum;
  union { bf16_t h[2]; unsigned u; } pk;
  pk.h[0] = (bf16_t)(p0 * inv);
  pk.h[1] = (bf16_t)(p1 * inv);
  *(unsigned*)(attnb + (size_t)bh * 4096 + rowoff) = pk.u;
}

// ---------------- xf = Q @ attn^T (MFMA), x2 = xb + xf, hln = LN(x2) ----------------
__global__ __launch_bounds__(256, 2)
void xf_ln_mfma_kernel(const bf16_t* __restrict__ qkv, const bf16_t* __restrict__ attnb,
                       const bf16_t* __restrict__ xb, bf16_t* __restrict__ x2b,
                       bf16_t* __restrict__ hln, const float* __restrict__ gamma,
                       const float* __restrict__ beta) {
  __shared__ __align__(16) unsigned char qs[32768];
  __shared__ float red[4][4][16][2];
  const int tid = threadIdx.x;
  const int row0 = blockIdx.x * 64;
  const int b = row0 >> 12;
  const int lane = tid & 63, h = tid >> 6;
  const int lr = lane & 15, lk = lane >> 4;

#pragma unroll
  for (int i = 0; i < 8; ++i) {
    int idx = i * 256 + tid;
    int row = idx >> 5, pk = idx & 31;
    gll16(qkv + (size_t)(row0 + row) * HID + ((pk ^ (row & 7)) * 8), qs + idx * 16);
  }
  asm volatile("s_waitcnt vmcnt(0)" ::: "memory");
  __builtin_amdgcn_s_barrier();

  bf16x8 af[4][2];
#pragma unroll
  for (int mi = 0; mi < 4; ++mi)
#pragma unroll
    for (int kk = 0; kk < 2; ++kk) {
      int row = mi * 16 + lr;
      int pk = h * 8 + kk * 4 + lk;
      af[mi][kk] = *(const bf16x8*)(qs + row * 512 + ((pk ^ (row & 7)) * 16));
    }
  bf16x8 bfr[4][2];
#pragma unroll
  for (int nf = 0; nf < 4; ++nf)
#pragma unroll
    for (int kk = 0; kk < 2; ++kk)
      bfr[nf][kk] = *(const bf16x8*)(attnb + (size_t)(b * 4 + h) * 4096 +
                                     (nf * 16 + lr) * 64 + kk * 32 + lk * 8);
  f32x4 acc[4][4] = {};
#pragma unroll
  for (int kk = 0; kk < 2; ++kk)
#pragma unroll
    for (int mi = 0; mi < 4; ++mi)
#pragma unroll
      for (int nf = 0; nf < 4; ++nf)
        acc[mi][nf] = __builtin_amdgcn_mfma_f32_16x16x32_bf16(bfr[nf][kk], af[mi][kk], acc[mi][nf], 0, 0, 0);

  float ps[4], pq[4];
#pragma unroll
  for (int mi = 0; mi < 4; ++mi) {
    ps[mi] = 0.f; pq[mi] = 0.f;
    int row = row0 + mi * 16 + lr;
#pragma unroll
    for (int nf = 0; nf < 4; ++nf) {
      int col = h * 64 + nf * 16 + lk * 4;
      size_t off = (size_t)row * DIMC + col;
      bf16x4 xv = *(const bf16x4*)(xb + off);
      f32x4 x2;
#pragma unroll
      for (int r = 0; r < 4; ++r) {
        x2[r] = acc[mi][nf][r] + (float)xv[r];
        ps[mi] += x2[r]; pq[mi] += x2[r] * x2[r];
      }
      acc[mi][nf] = x2;
      bf16x4 o;
#pragma unroll
      for (int r = 0; r < 4; ++r) o[r] = (bf16_t)x2[r];
      *(bf16x4*)(x2b + off) = o;
    }
#pragma unroll
    for (int m = 16; m < 64; m <<= 1) {
      ps[mi] += __shfl_xor(ps[mi], m);
      pq[mi] += __shfl_xor(pq[mi], m);
    }
  }
  if (lk == 0) {
#pragma unroll
    for (int mi = 0; mi < 4; ++mi) { red[h][mi][lr][0] = ps[mi]; red[h][mi][lr][1] = pq[mi]; }
  }
  __builtin_amdgcn_s_barrier();
#pragma unroll
  for (int mi = 0; mi < 4; ++mi) {
    float t1 = red[0][mi][lr][0] + red[1][mi][lr][0] + red[2][mi][lr][0] + red[3][mi][lr][0];
    float t2 = red[0][mi][lr][1] + red[1][mi][lr][1] + red[2][mi][lr][1] + red[3][mi][lr][1];
    float mu = t1 * (1.0f / 256.0f);
    float var = t2 * (1.0f / 256.0f) - mu * mu;
    float rs = rsqrtf(var + 1e-5f);
    int row = row0 + mi * 16 + lr;
#pragma unroll
    for (int nf = 0; nf < 4; ++nf) {
      int col = h * 64 + nf * 16 + lk * 4;
      f32x4 g4 = *(const f32x4*)(gamma + col);
      f32x4 b4 = *(const f32x4*)(beta + col);
      bf16x4 o;
#pragma unroll
      for (int r = 0; r < 4; ++r)
        o[r] = (bf16_t)((acc[mi][nf][r] - mu) * rs * g4[r] + b4[r]);
      *(bf16x4*)(hln + (size_t)row * DIMC + col) = o;
    }
  }
}

extern "C" void kernel_launch(void* const* d_in, const int* in_sizes, int n_in,
                              void* d_out, int out_size, void* d_ws, size_t ws_size,
                              hipStream_t stream) {
  const float* x      = (const float*)d_in[0];
  const float* w_qkv  = (const float*)d_in[1];
  const float* b_qkv  = (const float*)d_in[2];
  const float* norm_g = (const float*)d_in[3];
  const float* norm_b = (const float*)d_in[4];
  const float* w_fc1  = (const float*)d_in[5];
  const float* b_fc1  = (const float*)d_in[6];
  const float* w_fc2  = (const float*)d_in[7];
  const float* b_fc2  = (const float*)d_in[8];

  char* ws = (char*)d_ws;
  size_t off = 0;
  bf16_t* qkv   = (bf16_t*)(ws + off); off += (size_t)ROWS * HID * 2;          // 50.3 MB (reused as mid)
  bf16_t* mid   = qkv;
  bf16_t* xb    = (bf16_t*)(ws + off); off += (size_t)ROWS * DIMC * 2;         // 16.8 MB
  bf16_t* hln   = (bf16_t*)(ws + off); off += (size_t)ROWS * DIMC * 2;         // 16.8 MB
  bf16_t* x2b   = (bf16_t*)(ws + off); off += (size_t)ROWS * DIMC * 2;         // 16.8 MB
  float*  part  = (float*)(ws + off);  off += (size_t)NCHUNK * 32 * 4096 * 4;  // 16.8 MB
  bf16_t* attnb = (bf16_t*)(ws + off); off += (size_t)32 * 4096 * 2;           // 0.26 MB
  bf16_t* Bq    = (bf16_t*)(ws + off); off += (size_t)768 * 256 * 2;
  bf16_t* B1    = (bf16_t*)(ws + off); off += (size_t)768 * 256 * 2;
  bf16_t* B2    = (bf16_t*)(ws + off); off += (size_t)256 * 768 * 2;

  // merged prep: x->bf16 (4096 blocks) + 3 weight packs (96 blocks each)
  prep_all_kernel<<<4384, 256, 0, stream>>>(x, xb, w_qkv, Bq, w_fc1, B1, w_fc2, B2);

  // qkv = x @ w_qkv + b_qkv    [32768 x 768]
  gemm_packed_kernel<0><<<dim3(4, ROWS / 32), 256, 0, stream>>>(xb, Bq, b_qkv, qkv);
  // attention
  attn_kv_kernel<<<dim3(32, NCHUNK), 256, 0, stream>>>(qkv, part);
  attn_softmax_kernel<<<dim3(32, 8), 256, 0, stream>>>(part, attnb);
  // xf + residual + layernorm (MFMA)
  xf_ln_mfma_kernel<<<ROWS / 64, 256, 0, stream>>>(qkv, attnb, xb, x2b, hln, norm_g, norm_b);
  // mid = gelu(hln @ w_fc1 + b_fc1)   [32768 x 768]
  gemm_packed_kernel<1><<<dim3(4, ROWS / 32), 256, 0, stream>>>(hln, B1, b_fc1, mid);
  // out = x2 + mid @ w_fc2 + b_fc2    [32768 x 256]
  fc2_packed_kernel<<<ROWS / 64, 256, 0, stream>>>(mid, B2, b_fc2, x2b, (float*)d_out);
}

// Round 19
// 119.678 us; speedup vs baseline: 1.0410x; 1.0410x over previous
//
#include <hip/hip_runtime.h>
#include <math.h>

typedef __bf16 bf16_t;
typedef __bf16 bf16x4 __attribute__((ext_vector_type(4)));
typedef __bf16 bf16x8 __attribute__((ext_vector_type(8)));
typedef float f32x4 __attribute__((ext_vector_type(4)));

#define DIMC 256
#define HID 768
#define NB 8
#define NN 4096
#define ROWS (NB*NN)   /* 32768 */
#define NCHUNK 32

#define AS1 __attribute__((address_space(1)))
#define AS3 __attribute__((address_space(3)))

__device__ __forceinline__ void gll16(const bf16_t* src, void* lds) {
  __builtin_amdgcn_global_load_lds((const AS1 void*)src, (AS3 void*)lds, 16, 0, 0);
}

__device__ __forceinline__ float gelu_exact(float v) {
  return 0.5f * v * (1.0f + erff(v * 0.70710678118654752f));
}

// ---- pack weight w[K][Nw] (f32) into MFMA-fragment order bf16 (device body) ----
__device__ __forceinline__ void pack_w_body(int idx, const float* __restrict__ w,
                                            bf16_t* __restrict__ out, int K, int Nw) {
  int lane = idx & 63;
  int kq = (idx >> 6) % (K >> 5);
  int nt = idx / ((K >> 5) << 6);
  int n = nt * 16 + (lane & 15);
  int k0 = kq * 32 + (lane >> 4) * 8;
  bf16x8 o;
#pragma unroll
  for (int j = 0; j < 8; ++j) o[j] = (bf16_t)w[(size_t)(k0 + j) * Nw + n];
  *(bf16x8*)(out + (size_t)idx * 8) = o;
}

// ---------------- merged prep: x->bf16 + 3x weight pack (one dispatch) ----------------
__global__ __launch_bounds__(256)
void prep_all_kernel(const float* __restrict__ x, bf16_t* __restrict__ xb,
                     const float* __restrict__ w_qkv, bf16_t* __restrict__ Bq,
                     const float* __restrict__ w_fc1, bf16_t* __restrict__ B1,
                     const float* __restrict__ w_fc2, bf16_t* __restrict__ B2) {
  const int bid = blockIdx.x, tid = threadIdx.x;
  if (bid < 4096) {
    int i = (bid * 256 + tid) * 8;
    f32x4 a = *(const f32x4*)(x + i);
    f32x4 b = *(const f32x4*)(x + i + 4);
    bf16x8 o;
    o[0] = (bf16_t)a[0]; o[1] = (bf16_t)a[1]; o[2] = (bf16_t)a[2]; o[3] = (bf16_t)a[3];
    o[4] = (bf16_t)b[0]; o[5] = (bf16_t)b[1]; o[6] = (bf16_t)b[2]; o[7] = (bf16_t)b[3];
    *(bf16x8*)(xb + i) = o;
  } else if (bid < 4192) {
    pack_w_body((bid - 4096) * 256 + tid, w_qkv, Bq, 256, 768);
  } else if (bid < 4288) {
    pack_w_body((bid - 4192) * 256 + tid, w_fc1, B1, 256, 768);
  } else {
    pack_w_body((bid - 4288) * 256 + tid, w_fc2, B2, 768, 256);
  }
}

// ============ packed-B GEMM: C[M,768] = A[M,256] @ W + bias ============
// r15 proven-best structure: 64x192 tiles, 2048 blocks, XCD-chunked swizzle,
// 2-deep B prefetch, 1-deep A, setprio around MFMA cluster.
template <int EPI>
__global__ __launch_bounds__(256, 2)
void gemm_packed_kernel(const bf16_t* __restrict__ A, const bf16_t* __restrict__ Bp,
                        const float* __restrict__ bias, bf16_t* __restrict__ outp) {
  __shared__ __align__(16) unsigned char smem[32768];
  const int tid = threadIdx.x;
  const int d = blockIdx.x + blockIdx.y * 4;
  const int w_ = (d & 7) * 256 + (d >> 3);
  const int panel = w_ & 3, rowb = w_ >> 2;
  const int m0 = rowb * 64;
  const int n0 = panel * 192;
  const int lane = tid & 63, w = tid >> 6;
  const int lr = lane & 15, lk = lane >> 4;

  // stage A 64x256 (full 512B rows, 2 rows per wave-instr)
#pragma unroll
  for (int i = 0; i < 8; ++i) {
    int idx = i * 256 + tid;
    int row = idx >> 5, pk = idx & 31;
    gll16(A + (size_t)(m0 + row) * 256 + ((pk ^ (row & 7)) * 8), smem + idx * 16);
  }
  asm volatile("s_waitcnt vmcnt(0)" ::: "memory");
  __builtin_amdgcn_s_barrier();

  f32x4 acc[4][3] = {};
  const bf16_t* bb = Bp + (size_t)((panel * 12 + w * 3) * 8) * 512 + lane * 8;

  bf16x8 bf[3][3];   // rotating 3-slot B (2-deep prefetch); static idx under unroll
  bf16x8 af[2][4];   // rotating 2-slot A
#pragma unroll
  for (int nf = 0; nf < 3; ++nf) {
    bf[0][nf] = *(const bf16x8*)(bb + (nf * 8 + 0) * 512);
    bf[1][nf] = *(const bf16x8*)(bb + (nf * 8 + 1) * 512);
  }
#pragma unroll
  for (int mi = 0; mi < 4; ++mi) {
    int row = mi * 16 + lr;
    af[0][mi] = *(const bf16x8*)(smem + row * 512 + ((lk ^ (row & 7)) * 16));
  }

#pragma unroll
  for (int kq = 0; kq < 8; ++kq) {
    if (kq < 6) {
#pragma unroll
      for (int nf = 0; nf < 3; ++nf)
        bf[(kq + 2) % 3][nf] = *(const bf16x8*)(bb + (nf * 8 + kq + 2) * 512);
    }
    if (kq < 7) {
#pragma unroll
      for (int mi = 0; mi < 4; ++mi) {
        int row = mi * 16 + lr;
        af[(kq + 1) & 1][mi] =
            *(const bf16x8*)(smem + row * 512 + ((((kq + 1) * 4 + lk) ^ (row & 7)) * 16));
      }
    }
    __builtin_amdgcn_s_setprio(1);
#pragma unroll
    for (int nf = 0; nf < 3; ++nf)
#pragma unroll
      for (int mi = 0; mi < 4; ++mi)
        acc[mi][nf] = __builtin_amdgcn_mfma_f32_16x16x32_bf16(bf[kq % 3][nf], af[kq & 1][mi],
                                                              acc[mi][nf], 0, 0, 0);
    __builtin_amdgcn_s_setprio(0);
  }

  // ---- epilogue: reuse A-LDS (64 rows x 384B), single phase ----
  f32x4 bs[3];
#pragma unroll
  for (int nf = 0; nf < 3; ++nf)
    bs[nf] = *(const f32x4*)(bias + n0 + w * 48 + nf * 16 + lk * 4);

  __syncthreads();
#pragma unroll
  for (int mi = 0; mi < 4; ++mi) {
    int row_l = mi * 16 + lr;
#pragma unroll
    for (int nf = 0; nf < 3; ++nf) {
      int col = w * 48 + nf * 16 + lk * 4;   // block-local 0..191
      f32x4 v = acc[mi][nf] + bs[nf];
      bf16x4 o;
#pragma unroll
      for (int r = 0; r < 4; ++r) {
        float val = v[r];
        if (EPI == 1) val = gelu_exact(val);
        o[r] = (bf16_t)val;
      }
      int chunk = col >> 3;
      int half = (col >> 2) & 1;
      *(bf16x4*)(smem + row_l * 384 + ((chunk ^ (row_l & 7)) << 4) + (half << 3)) = o;
    }
  }
  __syncthreads();
#pragma unroll
  for (int i = 0; i < 6; ++i) {
    int id = i * 256 + tid;
    int row_l = id / 24, c = id % 24;
    bf16x8 v = *(const bf16x8*)(smem + row_l * 384 + ((c ^ (row_l & 7)) << 4));
    *(bf16x8*)(outp + (size_t)(m0 + row_l) * 768 + n0 + c * 8) = v;
  }
}

// ============ fc2: out[M,256] = mid[M,768] @ W + bias + resid (f32 out) ============
__global__ __launch_bounds__(256, 2)
void fc2_packed_kernel(const bf16_t* __restrict__ mid, const bf16_t* __restrict__ Bp,
                       const float* __restrict__ bias, const bf16_t* __restrict__ resid,
                       float* __restrict__ outp) {
  __shared__ __align__(16) unsigned char smem[2 * 16384 + 32768];
  unsigned char* epi = smem + 32768;
  const int tid = threadIdx.x;
  const int m0 = blockIdx.x * 64;
  const int lane = tid & 63, w = tid >> 6;
  const int lr = lane & 15, lk = lane >> 4;

  auto stageA = [&](int c, int buf) {
#pragma unroll
    for (int i = 0; i < 4; ++i) {
      int idx = i * 256 + tid;
      int row = idx >> 4, pk = idx & 15;
      gll16(mid + (size_t)(m0 + row) * 768 + c * 128 + ((pk ^ (row & 7)) * 8),
            smem + buf * 16384 + idx * 16);
    }
  };

  stageA(0, 0);
  stageA(1, 1);
  asm volatile("s_waitcnt vmcnt(4)" ::: "memory");
  __builtin_amdgcn_s_barrier();

  f32x4 acc[4][4] = {};
#pragma unroll
  for (int c = 0; c < 6; ++c) {
    bf16x8 bf[4][4];
#pragma unroll
    for (int nf = 0; nf < 4; ++nf)
#pragma unroll
      for (int kql = 0; kql < 4; ++kql)
        bf[nf][kql] = *(const bf16x8*)(Bp + (size_t)((w * 4 + nf) * 24 + c * 4 + kql) * 512 + lane * 8);
    asm volatile("s_waitcnt vmcnt(0)" ::: "memory");
    __builtin_amdgcn_s_barrier();
#pragma unroll
    for (int kql = 0; kql < 4; ++kql) {
#pragma unroll
      for (int mi = 0; mi < 4; ++mi) {
        int row = mi * 16 + lr;
        bf16x8 a8 = *(const bf16x8*)(smem + (c & 1) * 16384 + row * 256 +
                                     (((kql * 4 + lk) ^ (row & 7)) * 16));
#pragma unroll
        for (int nf = 0; nf < 4; ++nf)
          acc[mi][nf] = __builtin_amdgcn_mfma_f32_16x16x32_bf16(bf[nf][kql], a8, acc[mi][nf], 0, 0, 0);
      }
    }
    __builtin_amdgcn_s_barrier();
    if (c + 2 < 6) stageA(c + 2, c & 1);
  }

  f32x4 bs[4];
#pragma unroll
  for (int nf = 0; nf < 4; ++nf)
    bs[nf] = *(const f32x4*)(bias + w * 64 + nf * 16 + lk * 4);

#pragma unroll
  for (int ph = 0; ph < 2; ++ph) {
    if (ph == 1) __syncthreads();
#pragma unroll
    for (int mj = 0; mj < 2; ++mj) {
      int mi = ph * 2 + mj;
      int row_l = mj * 16 + lr;
#pragma unroll
      for (int nf = 0; nf < 4; ++nf) {
        int cc = w * 64 + nf * 16 + lk * 4;
        f32x4 v = acc[mi][nf] + bs[nf];
        int chunk = cc >> 2;
        *(f32x4*)(epi + row_l * 1024 + ((chunk ^ (row_l & 7)) << 4)) = v;
      }
    }
    __syncthreads();
#pragma unroll
    for (int i = 0; i < 8; ++i) {
      int id = i * 256 + tid;
      int rl = id >> 6, c = id & 63;
      f32x4 v = *(const f32x4*)(epi + rl * 1024 + ((c ^ (rl & 7)) << 4));
      int grow = m0 + ph * 32 + rl;
      bf16x4 rz = *(const bf16x4*)(resid + (size_t)grow * 256 + c * 4);
#pragma unroll
      for (int r = 0; r < 4; ++r) v[r] += (float)rz[r];
      *(f32x4*)(outp + (size_t)grow * 256 + c * 4) = v;
    }
  }
}

// ---------------- attention: partial K^T V over N-chunks (VALU), bf16 partials ----------------
__global__ __launch_bounds__(256)
void attn_kv_kernel(const bf16_t* __restrict__ qkv, bf16_t* __restrict__ part) {
  const int bh = blockIdx.x, chunk = blockIdx.y;
  const int b = bh >> 2, h = bh & 3;
  __shared__ __align__(16) float kl[32][68];
  __shared__ __align__(16) float vl[32][68];
  const int tid = threadIdx.x;
  const int dg = tid >> 4, eg = tid & 15;
  f32x4 acc[4] = {};
  const int n00 = chunk * (NN / NCHUNK);
  const int srow = tid >> 3, spk = tid & 7;
  for (int t = 0; t < (NN / NCHUNK) / 32; ++t) {
    int n0 = n00 + t * 32;
    {
      const bf16x8 k8 = *(const bf16x8*)(qkv + (size_t)(b * NN + n0 + srow) * HID + 256 + h * 64 + spk * 8);
      const bf16x8 v8 = *(const bf16x8*)(qkv + (size_t)(b * NN + n0 + srow) * HID + 512 + h * 64 + spk * 8);
#pragma unroll
      for (int j = 0; j < 8; ++j) kl[srow][spk * 8 + j] = (float)k8[j];
#pragma unroll
      for (int j = 0; j < 8; ++j) vl[srow][spk * 8 + j] = (float)v8[j];
    }
    __syncthreads();
#pragma unroll 8
    for (int n = 0; n < 32; ++n) {
      f32x4 k4 = *(const f32x4*)&kl[n][dg * 4];
      f32x4 v4 = *(const f32x4*)&vl[n][eg * 4];
#pragma unroll
      for (int i = 0; i < 4; ++i) acc[i] += k4[i] * v4;
    }
    __syncthreads();
  }
  bf16_t* dst = part + (size_t)(chunk * 32 + bh) * 4096;
#pragma unroll
  for (int i = 0; i < 4; ++i) {
    bf16x4 o;
#pragma unroll
    for (int j = 0; j < 4; ++j) o[j] = (bf16_t)acc[i][j];
    *(bf16x4*)&dst[(dg * 4 + i) * 64 + eg * 4] = o;
  }
}

// ---------------- reduce bf16 partials + scale + softmax -> bf16 attn ----------------
// Grid (32 bh, 8 dgroups) = 256 blocks; 8 d-rows/block; 2 rows per wave.
__global__ __launch_bounds__(256)
void attn_softmax_kernel(const bf16_t* __restrict__ part, bf16_t* __restrict__ attnb) {
  const int bh = blockIdx.x, dg = blockIdx.y;
  const int tid = threadIdx.x;
  const int rl = tid >> 5, l32 = tid & 31;   // row-local 0..7, lane-in-row
  const int d = dg * 8 + rl;
  const size_t rowoff = (size_t)d * 64 + l32 * 2;
  float s0 = 0.f, s1 = 0.f;
  for (int c = 0; c < NCHUNK; ++c) {
    const bf16_t* src = part + (size_t)(c * 32 + bh) * 4096 + rowoff;
    s0 += (float)src[0]; s1 += (float)src[1];
  }
  float l0 = s0 * 0.125f, l1 = s1 * 0.125f;   // k-scale 1/sqrt(64)
  float m = fmaxf(l0, l1);
#pragma unroll
  for (int msk = 1; msk <= 16; msk <<= 1) m = fmaxf(m, __shfl_xor(m, msk));
  float p0 = expf(l0 - m), p1 = expf(l1 - m);
  float sum = p0 + p1;
#pragma unroll
  for (int msk = 1; msk <= 16; msk <<= 1) sum += __shfl_xor(sum, msk);
  float inv = 1.0f / sum;
  union { bf16_t h[2]; unsigned u; } pk;
  pk.h[0] = (bf16_t)(p0 * inv);
  pk.h[1] = (bf16_t)(p1 * inv);
  *(unsigned*)(attnb + (size_t)bh * 4096 + rowoff) = pk.u;
}

// ---------------- xf = Q @ attn^T (MFMA), x2 = xb + xf, hln = LN(x2) ----------------
__global__ __launch_bounds__(256, 2)
void xf_ln_mfma_kernel(const bf16_t* __restrict__ qkv, const bf16_t* __restrict__ attnb,
                       const bf16_t* __restrict__ xb, bf16_t* __restrict__ x2b,
                       bf16_t* __restrict__ hln, const float* __restrict__ gamma,
                       const float* __restrict__ beta) {
  __shared__ __align__(16) unsigned char qs[32768];
  __shared__ float red[4][4][16][2];
  const int tid = threadIdx.x;
  const int row0 = blockIdx.x * 64;
  const int b = row0 >> 12;
  const int lane = tid & 63, h = tid >> 6;
  const int lr = lane & 15, lk = lane >> 4;

#pragma unroll
  for (int i = 0; i < 8; ++i) {
    int idx = i * 256 + tid;
    int row = idx >> 5, pk = idx & 31;
    gll16(qkv + (size_t)(row0 + row) * HID + ((pk ^ (row & 7)) * 8), qs + idx * 16);
  }
  asm volatile("s_waitcnt vmcnt(0)" ::: "memory");
  __builtin_amdgcn_s_barrier();

  bf16x8 af[4][2];
#pragma unroll
  for (int mi = 0; mi < 4; ++mi)
#pragma unroll
    for (int kk = 0; kk < 2; ++kk) {
      int row = mi * 16 + lr;
      int pk = h * 8 + kk * 4 + lk;
      af[mi][kk] = *(const bf16x8*)(qs + row * 512 + ((pk ^ (row & 7)) * 16));
    }
  bf16x8 bfr[4][2];
#pragma unroll
  for (int nf = 0; nf < 4; ++nf)
#pragma unroll
    for (int kk = 0; kk < 2; ++kk)
      bfr[nf][kk] = *(const bf16x8*)(attnb + (size_t)(b * 4 + h) * 4096 +
                                     (nf * 16 + lr) * 64 + kk * 32 + lk * 8);
  f32x4 acc[4][4] = {};
#pragma unroll
  for (int kk = 0; kk < 2; ++kk)
#pragma unroll
    for (int mi = 0; mi < 4; ++mi)
#pragma unroll
      for (int nf = 0; nf < 4; ++nf)
        acc[mi][nf] = __builtin_amdgcn_mfma_f32_16x16x32_bf16(bfr[nf][kk], af[mi][kk], acc[mi][nf], 0, 0, 0);

  float ps[4], pq[4];
#pragma unroll
  for (int mi = 0; mi < 4; ++mi) {
    ps[mi] = 0.f; pq[mi] = 0.f;
    int row = row0 + mi * 16 + lr;
#pragma unroll
    for (int nf = 0; nf < 4; ++nf) {
      int col = h * 64 + nf * 16 + lk * 4;
      size_t off = (size_t)row * DIMC + col;
      bf16x4 xv = *(const bf16x4*)(xb + off);
      f32x4 x2;
#pragma unroll
      for (int r = 0; r < 4; ++r) {
        x2[r] = acc[mi][nf][r] + (float)xv[r];
        ps[mi] += x2[r]; pq[mi] += x2[r] * x2[r];
      }
      acc[mi][nf] = x2;
      bf16x4 o;
#pragma unroll
      for (int r = 0; r < 4; ++r) o[r] = (bf16_t)x2[r];
      *(bf16x4*)(x2b + off) = o;
    }
#pragma unroll
    for (int m = 16; m < 64; m <<= 1) {
      ps[mi] += __shfl_xor(ps[mi], m);
      pq[mi] += __shfl_xor(pq[mi], m);
    }
  }
  if (lk == 0) {
#pragma unroll
    for (int mi = 0; mi < 4; ++mi) { red[h][mi][lr][0] = ps[mi]; red[h][mi][lr][1] = pq[mi]; }
  }
  __builtin_amdgcn_s_barrier();
#pragma unroll
  for (int mi = 0; mi < 4; ++mi) {
    float t1 = red[0][mi][lr][0] + red[1][mi][lr][0] + red[2][mi][lr][0] + red[3][mi][lr][0];
    float t2 = red[0][mi][lr][1] + red[1][mi][lr][1] + red[2][mi][lr][1] + red[3][mi][lr][1];
    float mu = t1 * (1.0f / 256.0f);
    float var = t2 * (1.0f / 256.0f) - mu * mu;
    float rs = rsqrtf(var + 1e-5f);
    int row = row0 + mi * 16 + lr;
#pragma unroll
    for (int nf = 0; nf < 4; ++nf) {
      int col = h * 64 + nf * 16 + lk * 4;
      f32x4 g4 = *(const f32x4*)(gamma + col);
      f32x4 b4 = *(const f32x4*)(beta + col);
      bf16x4 o;
#pragma unroll
      for (int r = 0; r < 4; ++r)
        o[r] = (bf16_t)((acc[mi][nf][r] - mu) * rs * g4[r] + b4[r]);
      *(bf16x4*)(hln + (size_t)row * DIMC + col) = o;
    }
  }
}

extern "C" void kernel_launch(void* const* d_in, const int* in_sizes, int n_in,
                              void* d_out, int out_size, void* d_ws, size_t ws_size,
                              hipStream_t stream) {
  const float* x      = (const float*)d_in[0];
  const float* w_qkv  = (const float*)d_in[1];
  const float* b_qkv  = (const float*)d_in[2];
  const float* norm_g = (const float*)d_in[3];
  const float* norm_b = (const float*)d_in[4];
  const float* w_fc1  = (const float*)d_in[5];
  const float* b_fc1  = (const float*)d_in[6];
  const float* w_fc2  = (const float*)d_in[7];
  const float* b_fc2  = (const float*)d_in[8];

  char* ws = (char*)d_ws;
  size_t off = 0;
  bf16_t* qkv   = (bf16_t*)(ws + off); off += (size_t)ROWS * HID * 2;          // 50.3 MB (reused as mid)
  bf16_t* mid   = qkv;
  bf16_t* xb    = (bf16_t*)(ws + off); off += (size_t)ROWS * DIMC * 2;         // 16.8 MB
  bf16_t* hln   = (bf16_t*)(ws + off); off += (size_t)ROWS * DIMC * 2;         // 16.8 MB
  bf16_t* x2b   = (bf16_t*)(ws + off); off += (size_t)ROWS * DIMC * 2;         // 16.8 MB
  bf16_t* part  = (bf16_t*)(ws + off); off += (size_t)NCHUNK * 32 * 4096 * 2;  // 8.4 MB (bf16 partials)
  bf16_t* attnb = (bf16_t*)(ws + off); off += (size_t)32 * 4096 * 2;           // 0.26 MB
  bf16_t* Bq    = (bf16_t*)(ws + off); off += (size_t)768 * 256 * 2;
  bf16_t* B1    = (bf16_t*)(ws + off); off += (size_t)768 * 256 * 2;
  bf16_t* B2    = (bf16_t*)(ws + off); off += (size_t)256 * 768 * 2;

  // merged prep: x->bf16 (4096 blocks) + 3 weight packs (96 blocks each)
  prep_all_kernel<<<4384, 256, 0, stream>>>(x, xb, w_qkv, Bq, w_fc1, B1, w_fc2, B2);

  // qkv = x @ w_qkv + b_qkv    [32768 x 768]
  gemm_packed_kernel<0><<<dim3(4, ROWS / 64), 256, 0, stream>>>(xb, Bq, b_qkv, qkv);
  // attention
  attn_kv_kernel<<<dim3(32, NCHUNK), 256, 0, stream>>>(qkv, part);
  attn_softmax_kernel<<<dim3(32, 8), 256, 0, stream>>>(part, attnb);
  // xf + residual + layernorm (MFMA)
  xf_ln_mfma_kernel<<<ROWS / 64, 256, 0, stream>>>(qkv, attnb, xb, x2b, hln, norm_g, norm_b);
  // mid = gelu(hln @ w_fc1 + b_fc1)   [32768 x 768]
  gemm_packed_kernel<1><<<dim3(4, ROWS / 64), 256, 0, stream>>>(hln, B1, b_fc1, mid);
  // out = x2 + mid @ w_fc2 + b_fc2    [32768 x 256]
  fc2_packed_kernel<<<ROWS / 64, 256, 0, stream>>>(mid, B2, b_fc2, x2b, (float*)d_out);
}